// Round 1
// 545.796 us; speedup vs baseline: 1.3588x; 1.3588x over previous
//
#include <hip/hip_runtime.h>
#include <math.h>

namespace {
constexpr int Bb  = 8;
constexpr int Dd  = 384;
constexpr int HIN = 128;
constexpr int Cc  = 96;
constexpr int Nn  = 1024;
constexpr int NH  = 4;
constexpr int HD  = 24;
}
#define BN_EPS 1e-5f
#define QSCALE 0.20412414523193154f  /* 24^-0.5 */

typedef unsigned short u16;
typedef unsigned int   u32;
typedef __attribute__((ext_vector_type(8))) short bh8;   // 8 bf16 = 4 VGPR (MFMA A/B frag)
typedef __attribute__((ext_vector_type(4))) float fx4;   // MFMA C/D frag

#define MFMA16(a,b,c) __builtin_amdgcn_mfma_f32_16x16x32_bf16((a),(b),(c),0,0,0)

union PackU { u32 u[4]; bh8 s; };

// truncated hi/lo bf16 split: v == hi + lo to ~2^-16 relative
__device__ __forceinline__ void split1(float v, u16& hi, u16& lo) {
    const u32 bv = __float_as_uint(v);
    const u32 hb = bv & 0xffff0000u;
    hi = (u16)(bv >> 16);
    const float r = v - __uint_as_float(hb);   // exact (same exponent)
    lo = (u16)(__float_as_uint(r) >> 16);
}
// pack two floats into one dword of 2 bf16 (x->lo half, y->hi half) + residual pack
__device__ __forceinline__ void split2(float x, float y, u32& hi, u32& lo) {
    const u32 bx = __float_as_uint(x), by = __float_as_uint(y);
    const u32 hx = bx & 0xffff0000u, hy = by & 0xffff0000u;
    hi = (hx >> 16) | hy;
    const float rx = x - __uint_as_float(hx);
    const float ry = y - __uint_as_float(hy);
    lo = (__float_as_uint(rx) >> 16) | (__float_as_uint(ry) & 0xffff0000u);
}

__device__ __forceinline__ float bn_relu6(float y, const float* __restrict__ bn, int c) {
    float gam = bn[c], bet = bn[Cc + c], mu = bn[2*Cc + c], var = bn[3*Cc + c];
    float s = gam / sqrtf(var + BN_EPS);
    float r = (y - mu) * s + bet;
    return fminf(fmaxf(r, 0.0f), 6.0f);
}

// ---------------------------------------------------------------------------
// Stem: fused (grouped 4x4/s4 conv | 4x4 maxpool+grouped1x1 | 4x4 avgpool+grouped1x1)
// ---------------------------------------------------------------------------
__global__ __launch_bounds__(256) void stem_kernel(
    const float* __restrict__ x, const float* __restrict__ w_le,
    const float* __restrict__ b_le, const float* __restrict__ bn_le,
    const float* __restrict__ w_max, const float* __restrict__ b_max, const float* __restrict__ bn_max,
    const float* __restrict__ w_avg, const float* __restrict__ b_avg, const float* __restrict__ bn_avg,
    float* __restrict__ xq, float* __restrict__ tmx, float* __restrict__ tav)
{
    const int tid = threadIdx.x;
    const int n = blockIdx.x * 256 + tid;
    const int g = blockIdx.y;
    const int b = blockIdx.z;
    const int oh = n >> 5, ow = n & 31;

    const float* xb = x + (((size_t)b * Dd + 4*g) * HIN + 4*oh) * HIN + 4*ow;
    float conv = 0.0f, mxv = 0.0f, avv = 0.0f;
    #pragma unroll
    for (int i = 0; i < 4; ++i) {
        float cmax = -3.0e38f, csum = 0.0f;
        #pragma unroll
        for (int kh = 0; kh < 4; ++kh) {
            const float4 v = *(const float4*)(xb + ((size_t)i * HIN + kh) * HIN);
            const float* wl = w_le + (((g*4 + i)*4 + kh) * 4);
            conv = fmaf(v.x, wl[0], conv);
            conv = fmaf(v.y, wl[1], conv);
            conv = fmaf(v.z, wl[2], conv);
            conv = fmaf(v.w, wl[3], conv);
            cmax = fmaxf(cmax, fmaxf(fmaxf(v.x, v.y), fmaxf(v.z, v.w)));
            csum += (v.x + v.y) + (v.z + v.w);
        }
        mxv = fmaf(cmax, w_max[g*4 + i], mxv);
        avv = fmaf(csum * (1.0f/16.0f), w_avg[g*4 + i], avv);
    }
    const float xqv = bn_relu6(conv + b_le[g], bn_le, g);
    const float tm  = bn_relu6(mxv  + b_max[g], bn_max, g);
    const float ta  = bn_relu6(avv  + b_avg[g], bn_avg, g);
    const size_t o = ((size_t)b * Cc + g) * Nn + n;
    xq[o] = xqv; tmx[o] = tm; tav[o] = ta;
}

// ---------------------------------------------------------------------------
// Projections -> bf16 hi/lo MFMA operand layouts.
//   Q:  [bh][n][32]  (d pad 24..31 = 0; QSCALE pre-applied)
//   K:  [bh][rho(n)][32]  rows permuted within each 32-chunk:
//        row 32c+16t+4g+j holds key 32c+8g+4t+j  (so S^T C-frags line up with
//        the PV B-operand key slots with zero cross-lane traffic)
//   V^T:[bh][32][n]  (d rows 24..31 = 0)
// ---------------------------------------------------------------------------
__global__ __launch_bounds__(256) void proj_kernel(
    const float* __restrict__ xq, const float* __restrict__ tmx, const float* __restrict__ tav,
    const float* __restrict__ w_q, const float* __restrict__ w_kv,
    u16* __restrict__ qhp, u16* __restrict__ qlp,
    u16* __restrict__ k1h, u16* __restrict__ k1l, u16* __restrict__ k2h, u16* __restrict__ k2l,
    u16* __restrict__ v1h, u16* __restrict__ v1l, u16* __restrict__ v2h, u16* __restrict__ v2l)
{
    const int tid = threadIdx.x;
    const int n0 = blockIdx.x * 32;
    const int b  = blockIdx.y;
    __shared__ float axq[32*101];
    __shared__ float amx[32*101];
    __shared__ float aav[32*101];
    __shared__ float lw[96*97];

    for (int e = tid; e < 96*32; e += 256) {
        const int c = e >> 5, j = e & 31;
        const size_t src = ((size_t)b * Cc + c) * Nn + n0 + j;
        axq[j*101 + c] = xq[src];
        amx[j*101 + c] = tmx[src];
        aav[j*101 + c] = tav[src];
    }

    const int tn = (tid & 7) * 4;   // 4 rows (n)
    const int tc = (tid >> 3) * 3;  // 3 cols

    // ---- phase A: q ----
    __syncthreads();
    for (int e = tid; e < 96*96; e += 256) lw[(e/96)*97 + (e%96)] = w_q[e];
    __syncthreads();
    {
        float acc[4][3] = {};
        for (int k = 0; k < 96; ++k) {
            const float w0 = lw[k*97 + tc + 0];
            const float w1 = lw[k*97 + tc + 1];
            const float w2 = lw[k*97 + tc + 2];
            #pragma unroll
            for (int i = 0; i < 4; ++i) {
                const float a = axq[(tn+i)*101 + k];
                acc[i][0] = fmaf(a, w0, acc[i][0]);
                acc[i][1] = fmaf(a, w1, acc[i][1]);
                acc[i][2] = fmaf(a, w2, acc[i][2]);
            }
        }
        #pragma unroll
        for (int j = 0; j < 3; ++j) {
            const int col = tc + j, hh = col / HD, d = col - hh*HD;
            #pragma unroll
            for (int i = 0; i < 4; ++i) {
                const int n = n0 + tn + i;
                u16 hi, lo;
                split1(acc[i][j] * QSCALE, hi, lo);
                const size_t dst = ((size_t)(b*NH + hh)*Nn + n)*32 + d;
                qhp[dst] = hi; qlp[dst] = lo;
            }
        }
    }

    // ---- phase B: k halves ----
    __syncthreads();
    for (int e = tid; e < 96*96; e += 256) lw[(e/96)*97 + (e%96)] = w_kv[(e/96)*192 + (e%96)];
    __syncthreads();
    {
        float a1c[4][3] = {}, a2c[4][3] = {};
        for (int k = 0; k < 96; ++k) {
            const float w0 = lw[k*97 + tc + 0];
            const float w1 = lw[k*97 + tc + 1];
            const float w2 = lw[k*97 + tc + 2];
            #pragma unroll
            for (int i = 0; i < 4; ++i) {
                const float a1 = amx[(tn+i)*101 + k];
                const float a2 = aav[(tn+i)*101 + k];
                a1c[i][0] = fmaf(a1, w0, a1c[i][0]);
                a1c[i][1] = fmaf(a1, w1, a1c[i][1]);
                a1c[i][2] = fmaf(a1, w2, a1c[i][2]);
                a2c[i][0] = fmaf(a2, w0, a2c[i][0]);
                a2c[i][1] = fmaf(a2, w1, a2c[i][1]);
                a2c[i][2] = fmaf(a2, w2, a2c[i][2]);
            }
        }
        #pragma unroll
        for (int j = 0; j < 3; ++j) {
            const int col = tc + j, hh = col / HD, d = col - hh*HD;
            #pragma unroll
            for (int i = 0; i < 4; ++i) {
                const int n = n0 + tn + i;
                const int rho = (n & ~31) | ((n & 4) << 2) | ((n & 24) >> 1) | (n & 3);
                const size_t dst = ((size_t)(b*NH + hh)*Nn + rho)*32 + d;
                u16 hi, lo;
                split1(a1c[i][j], hi, lo); k1h[dst] = hi; k1l[dst] = lo;
                split1(a2c[i][j], hi, lo); k2h[dst] = hi; k2l[dst] = lo;
            }
        }
    }

    // ---- phase C: v halves (transposed store) ----
    __syncthreads();
    for (int e = tid; e < 96*96; e += 256) lw[(e/96)*97 + (e%96)] = w_kv[(e/96)*192 + 96 + (e%96)];
    __syncthreads();
    {
        float a1c[4][3] = {}, a2c[4][3] = {};
        for (int k = 0; k < 96; ++k) {
            const float w0 = lw[k*97 + tc + 0];
            const float w1 = lw[k*97 + tc + 1];
            const float w2 = lw[k*97 + tc + 2];
            #pragma unroll
            for (int i = 0; i < 4; ++i) {
                const float a1 = amx[(tn+i)*101 + k];
                const float a2 = aav[(tn+i)*101 + k];
                a1c[i][0] = fmaf(a1, w0, a1c[i][0]);
                a1c[i][1] = fmaf(a1, w1, a1c[i][1]);
                a1c[i][2] = fmaf(a1, w2, a1c[i][2]);
                a2c[i][0] = fmaf(a2, w0, a2c[i][0]);
                a2c[i][1] = fmaf(a2, w1, a2c[i][1]);
                a2c[i][2] = fmaf(a2, w2, a2c[i][2]);
            }
        }
        #pragma unroll
        for (int j = 0; j < 3; ++j) {
            const int col = tc + j, hh = col / HD, d = col - hh*HD;
            #pragma unroll
            for (int i = 0; i < 4; ++i) {
                const int n = n0 + tn + i;
                const size_t dst = ((size_t)(b*NH + hh)*32 + d)*Nn + n;
                u16 hi, lo;
                split1(a1c[i][j], hi, lo); v1h[dst] = hi; v1l[dst] = lo;
                split1(a2c[i][j], hi, lo); v2h[dst] = hi; v2l[dst] = lo;
            }
        }
    }

    // ---- pad zeroing: q/k d=24..31 (must be finite-zero: 0*NaN hazard), v rows 24..31
    for (int e = tid; e < 1024; e += 256) {
        const int hh = e >> 8;
        const int nn = (e >> 3) & 31;
        const int d  = 24 + (e & 7);
        const int n  = n0 + nn;
        const size_t kd = ((size_t)(b*NH + hh)*Nn + n)*32 + d;
        qhp[kd] = 0; qlp[kd] = 0;
        k1h[kd] = 0; k1l[kd] = 0; k2h[kd] = 0; k2l[kd] = 0;
        const size_t vd = ((size_t)(b*NH + hh)*32 + d)*Nn + n;
        v1h[vd] = 0; v1l[vd] = 0; v2h[vd] = 0; v2l[vd] = 0;
    }
}

// ---------------------------------------------------------------------------
// MFMA flash attention, both branches. 1 wave = 16 queries, loops 16 key-tiles
// of 64. S^T = K.Q^T (3-term split-bf16, bias as C-init), online softmax on
// the C-frags (query = lane&15, key spread over lane groups), then
// O^T = V^T.P^T -- K-row permutation makes P's C-frags be exactly the PV
// B-operand slots (in-lane dword packing only, no shuffles).
// ---------------------------------------------------------------------------
__global__ __launch_bounds__(256) void attn_kernel(
    const u16* __restrict__ qhp, const u16* __restrict__ qlp,
    const u16* __restrict__ k1h, const u16* __restrict__ k1l,
    const u16* __restrict__ k2h, const u16* __restrict__ k2l,
    const u16* __restrict__ v1h, const u16* __restrict__ v1l,
    const u16* __restrict__ v2h, const u16* __restrict__ v2l,
    const float* __restrict__ bias_table, float* __restrict__ osum)
{
    const int tid = threadIdx.x;
    const int h = blockIdx.y, b = blockIdx.z;
    const int bh = b*NH + h;

    __shared__ float biasl[3969];
    for (int e = tid; e < 3969; e += 256) biasl[e] = bias_table[e*NH + h];
    __syncthreads();

    const int lane = tid & 63;
    const int wave = tid >> 6;
    const int lg = lane >> 4;     // lane group 0..3
    const int lr = lane & 15;
    const int q  = blockIdx.x*64 + wave*16 + lr;
    const int yn = q >> 5, xn = q & 31;

    const size_t qoff = ((size_t)bh*Nn + q)*32 + lg*8;
    const bh8 qfh = *(const bh8*)(qhp + qoff);
    const bh8 qfl = *(const bh8*)(qlp + qoff);

    const size_t kbase = ((size_t)bh*Nn + lr)*32 + lg*8;
    const u16* kp1h = k1h + kbase;
    const u16* kp1l = k1l + kbase;
    const u16* kp2h = k2h + kbase;
    const u16* kp2l = k2l + kbase;
    const size_t vbase = ((size_t)bh*32 + lr)*Nn + lg*8;
    const u16* vp1h = v1h + vbase;
    const u16* vp1l = v1l + vbase;
    const u16* vp2h = v2h + vbase;
    const u16* vp2l = v2l + vbase;

    const fx4 zero = {0.0f, 0.0f, 0.0f, 0.0f};
    fx4 o1[2], o2[2];
    o1[0] = zero; o1[1] = zero; o2[0] = zero; o2[1] = zero;
    float m1 = -3.0e38f, m2 = -3.0e38f, l1 = 0.0f, l2 = 0.0f;

    for (int it = 0; it < 16; ++it) {
        const int kb = it*64;
        fx4 s1[4], s2[4];
        #pragma unroll
        for (int t = 0; t < 4; ++t) {
            const int ro = (kb + t*16)*32;
            const bh8 a1h = *(const bh8*)(kp1h + ro);
            const bh8 a1l = *(const bh8*)(kp1l + ro);
            const bh8 a2h = *(const bh8*)(kp2h + ro);
            const bh8 a2l = *(const bh8*)(kp2l + ro);
            // actual key of C elem (t, lg, j): kb + 32*(t>>1) + 4*(t&1) + 8*lg + j
            const int ym   = (kb >> 5) + (t >> 1);
            const int xmb  = (t & 1)*4 + lg*8;
            const int rowb = (yn - ym + 31)*63 + (xn + 31) - xmb;
            fx4 cb;
            #pragma unroll
            for (int j = 0; j < 4; ++j) cb[j] = biasl[rowb - j];
            fx4 u1 = cb, u2 = cb;
            u1 = MFMA16(a1h, qfh, u1);
            u1 = MFMA16(a1h, qfl, u1);
            u1 = MFMA16(a1l, qfh, u1);
            u2 = MFMA16(a2h, qfh, u2);
            u2 = MFMA16(a2h, qfl, u2);
            u2 = MFMA16(a2l, qfh, u2);
            s1[t] = u1; s2[t] = u2;
        }

        // tile max (lane holds 16 keys; 4 lanes per query -> xor 16,32)
        float t1 = s1[0][0], t2 = s2[0][0];
        #pragma unroll
        for (int t = 0; t < 4; ++t)
            #pragma unroll
            for (int j = 0; j < 4; ++j) {
                if (t | j) { t1 = fmaxf(t1, s1[t][j]); t2 = fmaxf(t2, s2[t][j]); }
            }
        t1 = fmaxf(t1, __shfl_xor(t1, 16));
        t1 = fmaxf(t1, __shfl_xor(t1, 32));
        t2 = fmaxf(t2, __shfl_xor(t2, 16));
        t2 = fmaxf(t2, __shfl_xor(t2, 32));
        const float M1 = fmaxf(m1, t1), M2 = fmaxf(m2, t2);
        const float c1 = __expf(m1 - M1), c2 = __expf(m2 - M2);
        m1 = M1; m2 = M2;
        l1 *= c1; l2 *= c2;
        o1[0] *= c1; o1[1] *= c1;
        o2[0] *= c2; o2[1] *= c2;

        float p1[4][4], p2[4][4];
        #pragma unroll
        for (int t = 0; t < 4; ++t)
            #pragma unroll
            for (int j = 0; j < 4; ++j) {
                const float e1 = __expf(s1[t][j] - M1);
                const float e2 = __expf(s2[t][j] - M2);
                p1[t][j] = e1; p2[t][j] = e2;
                l1 += e1; l2 += e2;
            }

        #pragma unroll
        for (int ch = 0; ch < 2; ++ch) {
            PackU b1h, b1l, b2h, b2l;
            split2(p1[2*ch  ][0], p1[2*ch  ][1], b1h.u[0], b1l.u[0]);
            split2(p1[2*ch  ][2], p1[2*ch  ][3], b1h.u[1], b1l.u[1]);
            split2(p1[2*ch+1][0], p1[2*ch+1][1], b1h.u[2], b1l.u[2]);
            split2(p1[2*ch+1][2], p1[2*ch+1][3], b1h.u[3], b1l.u[3]);
            split2(p2[2*ch  ][0], p2[2*ch  ][1], b2h.u[0], b2l.u[0]);
            split2(p2[2*ch  ][2], p2[2*ch  ][3], b2h.u[1], b2l.u[1]);
            split2(p2[2*ch+1][0], p2[2*ch+1][1], b2h.u[2], b2l.u[2]);
            split2(p2[2*ch+1][2], p2[2*ch+1][3], b2h.u[3], b2l.u[3]);
            const int vo0 = kb + ch*32;
            #pragma unroll
            for (int dt = 0; dt < 2; ++dt) {
                const size_t vo = (size_t)(dt*16)*Nn + vo0;
                const bh8 w1h = *(const bh8*)(vp1h + vo);
                const bh8 w1l = *(const bh8*)(vp1l + vo);
                const bh8 w2h = *(const bh8*)(vp2h + vo);
                const bh8 w2l = *(const bh8*)(vp2l + vo);
                o1[dt] = MFMA16(w1h, b1h.s, o1[dt]);
                o1[dt] = MFMA16(w1h, b1l.s, o1[dt]);
                o1[dt] = MFMA16(w1l, b1h.s, o1[dt]);
                o2[dt] = MFMA16(w2h, b2h.s, o2[dt]);
                o2[dt] = MFMA16(w2h, b2l.s, o2[dt]);
                o2[dt] = MFMA16(w2l, b2h.s, o2[dt]);
            }
        }
    }

    l1 += __shfl_xor(l1, 16); l1 += __shfl_xor(l1, 32);
    l2 += __shfl_xor(l2, 16); l2 += __shfl_xor(l2, 32);
    const float i1 = 1.0f / l1, i2 = 1.0f / l2;
    float* orow = osum + ((size_t)b*Nn + q)*Cc + h*HD;
    #pragma unroll
    for (int dt = 0; dt < 2; ++dt)
        #pragma unroll
        for (int j = 0; j < 4; ++j) {
            const int d = dt*16 + lg*4 + j;
            if (d < HD) orow[d] = o1[dt][j]*i1 + o2[dt][j]*i2;
        }
}

// ---------------------------------------------------------------------------
__global__ __launch_bounds__(256) void fusew_kernel(
    const float* __restrict__ w_proj, const float* __restrict__ b_proj,
    const float* __restrict__ w_out, const float* __restrict__ b_out,
    float* __restrict__ wf, float* __restrict__ bf)
{
    const int e = blockIdx.x * 256 + threadIdx.x;
    if (e < Cc * Dd) {
        const int c = e / Dd, o = e - c*Dd;
        const float* wp = w_proj + c*Cc;
        const float* wo = w_out + (size_t)o*Cc;
        float acc = 0.0f;
        for (int c2 = 0; c2 < Cc; ++c2) acc = fmaf(wp[c2], wo[c2], acc);
        wf[e] = acc;
    }
    if (e < Dd) {
        const float* wo = w_out + (size_t)e*Cc;
        float acc = 0.0f;
        for (int c = 0; c < Cc; ++c) acc = fmaf(b_proj[c], wo[c], acc);
        bf[e] = b_out[e] + 2.0f * acc;
    }
}

// ---------------------------------------------------------------------------
__global__ __launch_bounds__(256) void outgemm_kernel(
    const float* __restrict__ osum, const float* __restrict__ wf, const float* __restrict__ bf,
    float* __restrict__ outs)
{
    const int tid = threadIdx.x;
    const int n0 = blockIdx.x * 32;
    const int b  = blockIdx.y;
    __shared__ float ax[32*101];
    __shared__ float lw[96*132];
    for (int e = tid; e < 32*96; e += 256) {
        const int n = e / 96, c = e - n*96;
        ax[n*101 + c] = osum[((size_t)b*Nn + n0 + n)*Cc + c];
    }
    const int tn = (tid & 7) * 4;
    const int tj = (tid >> 3) * 4;
    for (int o0 = 0; o0 < Dd; o0 += 128) {
        __syncthreads();
        for (int e = tid; e < 96*128; e += 256) {
            const int c = e >> 7, j = e & 127;
            lw[c*132 + j] = wf[(size_t)c*Dd + o0 + j];
        }
        __syncthreads();
        float acc[4][4] = {};
        for (int c = 0; c < 96; ++c) {
            const float4 wv = *(const float4*)&lw[c*132 + tj];
            #pragma unroll
            for (int i = 0; i < 4; ++i) {
                const float a = ax[(tn+i)*101 + c];
                acc[i][0] = fmaf(a, wv.x, acc[i][0]);
                acc[i][1] = fmaf(a, wv.y, acc[i][1]);
                acc[i][2] = fmaf(a, wv.z, acc[i][2]);
                acc[i][3] = fmaf(a, wv.w, acc[i][3]);
            }
        }
        #pragma unroll
        for (int j = 0; j < 4; ++j) {
            const int o = o0 + tj + j;
            const float bb = bf[o];
            #pragma unroll
            for (int i = 0; i < 4; ++i)
                outs[((size_t)b*Dd + o)*Nn + n0 + tn + i] = acc[i][j] + bb;
        }
    }
}

// ---------------------------------------------------------------------------
__global__ __launch_bounds__(256) void upsample_kernel(
    const float* __restrict__ src, float* __restrict__ dst)
{
    const int gid = blockIdx.x * 256 + threadIdx.x;
    const int ox4 = gid & 31;
    const int oy  = (gid >> 5) & 127;
    const int bc  = gid >> 12;
    const float* s = src + (size_t)bc * 1024;
    const float sy = oy * (31.0f / 127.0f);
    const int y0 = (int)sy;
    const int y1 = min(y0 + 1, 31);
    const float wy = sy - (float)y0;
    const float* r0 = s + y0 * 32;
    const float* r1 = s + y1 * 32;
    float res[4];
    #pragma unroll
    for (int j = 0; j < 4; ++j) {
        const int ox = ox4 * 4 + j;
        const float sx = ox * (31.0f / 127.0f);
        const int x0 = (int)sx;
        const int x1 = min(x0 + 1, 31);
        const float wx = sx - (float)x0;
        const float t0 = r0[x0] * (1.0f - wx) + r0[x1] * wx;
        const float t1 = r1[x0] * (1.0f - wx) + r1[x1] * wx;
        res[j] = t0 * (1.0f - wy) + t1 * wy;
    }
    *(float4*)(dst + (size_t)gid * 4) = make_float4(res[0], res[1], res[2], res[3]);
}

// ---------------------------------------------------------------------------
extern "C" void kernel_launch(void* const* d_in, const int* in_sizes, int n_in,
                              void* d_out, int out_size, void* d_ws, size_t ws_size,
                              hipStream_t stream)
{
    const float* x      = (const float*)d_in[0];
    const float* w_le   = (const float*)d_in[1];
    const float* b_le   = (const float*)d_in[2];
    const float* bn_le  = (const float*)d_in[3];
    const float* w_max  = (const float*)d_in[4];
    const float* b_max  = (const float*)d_in[5];
    const float* bn_max = (const float*)d_in[6];
    const float* w_avg  = (const float*)d_in[7];
    const float* b_avg  = (const float*)d_in[8];
    const float* bn_avg = (const float*)d_in[9];
    const float* btab   = (const float*)d_in[10];
    const float* w_q    = (const float*)d_in[11];
    const float* w_kv   = (const float*)d_in[12];
    const float* w_proj = (const float*)d_in[13];
    const float* b_proj = (const float*)d_in[14];
    const float* w_out  = (const float*)d_in[15];
    const float* b_out  = (const float*)d_in[16];
    (void)in_sizes; (void)n_in; (void)out_size; (void)ws_size;

    float* ws = (float*)d_ws;
    const size_t T  = (size_t)Bb * Cc * Nn;          // 786432 floats
    const size_t AS = (size_t)Bb * NH * Nn * 32;     // 1048576 u16 per bf16 array

    float* xq   = ws + 0*T;
    float* tmx  = ws + 1*T;
    float* tav  = ws + 2*T;
    u16*  bb16  = (u16*)(ws + 3*T);                  // 10 bf16 arrays, 20 MB
    u16* qh  = bb16 + 0*AS;  u16* ql  = bb16 + 1*AS;
    u16* k1h = bb16 + 2*AS;  u16* k1l = bb16 + 3*AS;
    u16* k2h = bb16 + 4*AS;  u16* k2l = bb16 + 5*AS;
    u16* v1h = bb16 + 6*AS;  u16* v1l = bb16 + 7*AS;
    u16* v2h = bb16 + 8*AS;  u16* v2l = bb16 + 9*AS;
    float* osum = (float*)(bb16 + 10*AS);
    float* wf   = osum + T;
    float* bf   = wf + (size_t)Cc*Dd;
    float* outs = ws;   // aliases [ws, ws+4T): stem bufs + head of bf16 region,
                        // all dead once outgemm runs (stream-serial)

    stem_kernel<<<dim3(4, 96, 8), 256, 0, stream>>>(
        x, w_le, b_le, bn_le, w_max, b_max, bn_max, w_avg, b_avg, bn_avg, xq, tmx, tav);
    proj_kernel<<<dim3(32, 8), 256, 0, stream>>>(
        xq, tmx, tav, w_q, w_kv, qh, ql, k1h, k1l, k2h, k2l, v1h, v1l, v2h, v2l);
    fusew_kernel<<<dim3(144), 256, 0, stream>>>(w_proj, b_proj, w_out, b_out, wf, bf);
    attn_kernel<<<dim3(16, 4, 8), 256, 0, stream>>>(
        qh, ql, k1h, k1l, k2h, k2l, v1h, v1l, v2h, v2l, btab, osum);
    outgemm_kernel<<<dim3(32, 8), 256, 0, stream>>>(osum, wf, bf, outs);
    upsample_kernel<<<dim3(49152), 256, 0, stream>>>(outs, (float*)d_out);
}